// Round 17
// baseline (472.725 us; speedup 1.0000x reference)
//
#include <hip/hip_runtime.h>
#include <hip/hip_bf16.h>
#include <math.h>

#define B_IMG 64
#define C_DIM 192
#define HW 3136
#define NTOK (B_IMG*HW)      // 200704
#define NH 6
#define HD 32
#define WSZ 7
#define NTW 49
#define SS 3
#define NWIN 4096
#define NW64 262144          // NWIN*64, padded window-aligned token stride
#define MLPH 384
#define EPS 1e-5f
#define HS 216               // H tile stride (u16): rows 16B-aligned

typedef __attribute__((ext_vector_type(8))) short bfx8;
typedef __attribute__((ext_vector_type(4))) float f32x4;

__device__ __forceinline__ float u2f(unsigned short u){
    union { float f; unsigned int i; } v; v.i = ((unsigned int)u) << 16; return v.f;
}
__device__ __forceinline__ unsigned short f2u(float f){
    union { float f; unsigned int i; } v; v.f = f;
    unsigned int r = v.i + 0x7FFF + ((v.i >> 16) & 1);
    return (unsigned short)(r >> 16);
}
// packed f32x2 -> bf16x2 (RNE), 1 instruction
__device__ __forceinline__ unsigned int cvtpk(float lo, float hi){
    unsigned int r;
    asm("v_cvt_pk_bf16_f32 %0, %1, %2" : "=v"(r) : "v"(lo), "v"(hi));
    return r;
}
// async 16B global->LDS DMA (no VGPR round-trip). LDS dest = wave-uniform
// base + lane*16; global src is per-lane (XOR-permuted to realize swizzle).
__device__ __forceinline__ void gl_lds16(const void* g, void* l){
    __builtin_amdgcn_global_load_lds(
        (const __attribute__((address_space(1))) unsigned int*)g,
        (__attribute__((address_space(3))) unsigned int*)l, 16, 0, 0);
}
// tanh-form GELU via one __expf: 0.5v(1+tanh(0.79788456(v+0.044715v^3)))
//  = v * sigmoid(1.59576912(v+0.044715v^3)); max |err| ~3e-4 << bf16 quant.
__device__ __forceinline__ float gelu_t(float v){
    float u = -1.5957691216057308f * v * (1.0f + 0.044715f*v*v);
    return v / (1.0f + __expf(u));
}

__device__ __forceinline__ int rowmap(int w_, int n){
    int b  = w_ >> 6, wl = w_ & 63;
    int wy = wl >> 3, wx = wl & 7;
    int ty = n / 7,  tx = n % 7;
    int h = wy*7 + ty + SS; if (h >= 56) h -= 56;
    int w = wx*7 + tx + SS; if (w >= 56) w -= 56;
    return b*HW + h*56 + w;
}

// ---------------- P0: weight prep (fold LN affine + scale, bf16 transpose) ----
__global__ void __launch_bounds__(256) p0_prep(
    const float* Wq, const float* bq, const float* Wk, const float* bk,
    const float* Wv, const float* bv, const float* Wproj,
    const float* W1, const float* b1, const float* W2,
    const float* gq, const float* nbq, const float* gkv, const float* nbkv,
    const float* gffn, const float* nbffn,
    const float* rpb, const int* rel_idx, const float* attn_mask,
    unsigned short* WqkvT, unsigned short* WprojT, unsigned short* W1T, unsigned short* W2T,
    float* bias_qkv, float* b1_e, unsigned short* comb,
    float* colsum_qkv, float* colsum1)
{
    const float scale = 0.17677669529663687f;   // 1/sqrt(32)
    int id = blockIdx.x*256 + threadIdx.x;
    if (id < 110592){                       // WqkvT [576][192]
        int j = id/192, c = id - j*192;
        int which = j/192, col = j - which*192;
        float v;
        if (which==0)      v = scale*gq[c]*Wq[c*192+col];
        else if (which==1) v = gkv[c]*Wk[c*192+col];
        else               v = gkv[c]*Wv[c*192+col];
        WqkvT[id] = f2u(v);
    } else if (id < 147456){                // WprojT [192][192]
        int t = id-110592; int co = t/192, k = t-co*192;
        WprojT[t] = f2u(Wproj[k*192+co]);
    } else if (id < 221184){                // W1T [384][192]
        int t = id-147456; int j = t/192, c = t-j*192;
        W1T[t] = f2u(gffn[c]*W1[c*384+j]);
    } else if (id < 294912){                // W2T [192][384]
        int t = id-221184; int co = t/384, k = t-co*384;
        W2T[t] = f2u(W2[k*192+co]);
    } else if (id < 295488){                // bias_qkv [576]
        int j = id-294912; int which=j/192, col=j-which*192;
        float s;
        if (which==0){ s = bq[col]; for(int c=0;c<192;c++) s += nbq[c]*Wq[c*192+col]; s*=scale; }
        else if (which==1){ s = bk[col]; for(int c=0;c<192;c++) s += nbkv[c]*Wk[c*192+col]; }
        else { s = bv[col]; for(int c=0;c<192;c++) s += nbkv[c]*Wv[c*192+col]; }
        bias_qkv[j] = s;
    } else if (id < 295872){                // b1_e [384]
        int j = id-295488; float s = b1[j];
        for(int c=0;c<192;c++) s += nbffn[c]*W1[c*384+j];
        b1_e[j] = s;
    } else if (id < 394176){                // comb [4][6][64][64] bf16
        int t = id-295872;
        int j = t & 63, i = (t>>6) & 63;
        int rest = t >> 12;                 // 0..23
        int h = rest % 6, cls = rest / 6;
        float v = -1e30f;
        if (i < 49 && j < 49){
            int wlrep = (cls>>1)*56 + (cls&1)*7;
            v = rpb[rel_idx[i*49+j]*6 + h] + attn_mask[wlrep*2401 + i*49 + j];
        }
        comb[t] = f2u(v);
    } else if (id < 394752){                // colsum_qkv [576]
        int j = id-394176; int which=j/192, col=j-which*192;
        float s = 0.f;
        if (which==0){ for(int c=0;c<192;c++) s += gq[c]*Wq[c*192+col]; s*=scale; }
        else if (which==1){ for(int c=0;c<192;c++) s += gkv[c]*Wk[c*192+col]; }
        else { for(int c=0;c<192;c++) s += gkv[c]*Wv[c*192+col]; }
        colsum_qkv[j] = s;
    } else if (id < 395136){                // colsum1 [384]
        int j = id-394752; float s = 0.f;
        for(int c=0;c<192;c++) s += gffn[c]*W1[c*384+j];
        colsum1[j] = s;
    }
}

// ---------------- P1: (B,C,HW) -> token-major bf16 X + LN stats ----------
__global__ void __launch_bounds__(256) p1_transpose_stats(
    const float* q, unsigned short* X, float* mean, float* rstd)
{
    __shared__ float t[32*193];
    __shared__ float ms[32], rs[32];
    int blk = blockIdx.x;
    int b = blk / 98, tile = blk - b*98;
    int hw0 = tile*32;
    const float* qb = q + (size_t)b*C_DIM*HW;
    int hw_off = threadIdx.x & 31, csub = threadIdx.x >> 5;
    for (int cb = 0; cb < 192; cb += 8){
        int c = cb + csub;
        t[hw_off*193 + c] = qb[(size_t)c*HW + hw0 + hw_off];
    }
    __syncthreads();
    {   // stats: 8 lanes per token
        int tt = threadIdx.x >> 3, qq = threadIdx.x & 7;
        float s=0.f, s2=0.f;
        #pragma unroll
        for (int i=0;i<24;i++){ float v = t[tt*193 + qq*24 + i]; s+=v; s2+=v*v; }
        s  += __shfl_xor(s,1);  s  += __shfl_xor(s,2);  s  += __shfl_xor(s,4);
        s2 += __shfl_xor(s2,1); s2 += __shfl_xor(s2,2); s2 += __shfl_xor(s2,4);
        if (qq==0){
            float m = s*(1.f/192.f);
            ms[tt] = m; rs[tt] = rsqrtf(s2*(1.f/192.f) - m*m + EPS);
        }
    }
    __syncthreads();
    int g0 = b*HW + hw0;
    if (threadIdx.x < 32){
        mean[g0+threadIdx.x] = ms[threadIdx.x];
        rstd[g0+threadIdx.x] = rs[threadIdx.x];
    }
    for (int i = threadIdx.x; i < 32*24; i += 256){
        int tt = i/24, cq = i - tt*24;
        int base = tt*193 + cq*8;
        int4 vr; unsigned int* pu = (unsigned int*)&vr;
        pu[0] = cvtpk(t[base+0], t[base+1]);
        pu[1] = cvtpk(t[base+2], t[base+3]);
        pu[2] = cvtpk(t[base+4], t[base+5]);
        pu[3] = cvtpk(t[base+6], t[base+7]);
        *(int4*)(X + (size_t)(g0+tt)*192 + cq*8) = vr;
    }
}

// ---------------- P2: QKV GEMM, async staging + rank-1 LN fold (R9) ------
__global__ void __launch_bounds__(256) p2_qkv(
    const unsigned short* X, const float* mean, const float* rstd,
    const unsigned short* WqkvT, const float* bias_qkv, const float* colsum_qkv,
    unsigned short* Qb, unsigned short* Kb, unsigned short* Vt)
{
    __shared__ __align__(16) char L[32768];      // As 8K | Bs 24K ; Cs 25.6K overlaps
    __shared__ int rowg[64];
    __shared__ __align__(16) float mr[64], rr[64];
    char* As = L; char* Bs = L + 8192;
    int which = blockIdx.y, bx = blockIdx.x;
    if (which < 2 && bx >= 3136) return;
    int t0 = bx*64;
    int tid = threadIdx.x, l = tid&63, wid = tid>>6;
    if (tid < 64){
        int w, n;
        if (which == 2){ w = bx; n = tid > 48 ? 48 : tid; }
        else { int t = t0 + tid; w = t/49; n = t - w*49; }
        int g = rowmap(w, n); rowg[tid]=g; mr[tid]=mean[g]; rr[tid]=rstd[g];
    }
    __syncthreads();
    f32x4 acc[4][3] = {};
    for (int kt=0; kt<3; ++kt){
        #pragma unroll
        for (int i=0;i<2;++i){                   // A: 512 slots
            int c = i*256 + tid;
            int row = c>>3, kq = (c&7) ^ (row&7);
            gl_lds16(X + (size_t)rowg[row]*192 + kt*64 + kq*8,
                     As + i*4096 + wid*1024);
        }
        #pragma unroll
        for (int i=0;i<6;++i){                   // B: 1536 slots
            int c = i*256 + tid;
            int row = c>>3, kq = (c&7) ^ (row&7);
            gl_lds16(WqkvT + (size_t)(which*192+row)*192 + kt*64 + kq*8,
                     Bs + i*4096 + wid*1024);
        }
        __syncthreads();
        #pragma unroll
        for (int ks2=0; ks2<2; ++ks2){
            int kb = ks2*64 + ((l>>4)*16);
            bfx8 a[4], b[3];
            #pragma unroll
            for (int m=0;m<4;m++){ int r = m*16 + (l&15); a[m] = *(const bfx8*)(As + r*128 + (kb ^ ((r&7)<<4))); }
            #pragma unroll
            for (int n=0;n<3;n++){ int r = (wid*3+n)*16 + (l&15); b[n] = *(const bfx8*)(Bs + r*128 + (kb ^ ((r&7)<<4))); }
            #pragma unroll
            for (int m=0;m<4;m++)
                #pragma unroll
                for (int n=0;n<3;n++)
                    acc[m][n] = __builtin_amdgcn_mfma_f32_16x16x32_bf16(a[m], b[n], acc[m][n], 0,0,0);
        }
        __syncthreads();
    }
    unsigned short* Cs = (unsigned short*)L;     // [64][200]
    #pragma unroll
    for (int m=0;m<4;m++){
        f32x4 m4 = *(const f32x4*)(mr + m*16 + (l>>4)*4);
        f32x4 r4 = *(const f32x4*)(rr + m*16 + (l>>4)*4);
        #pragma unroll
        for (int n=0;n<3;n++){
            int col = (wid*3+n)*16 + (l&15);
            float bv = bias_qkv[which*192 + col];
            float cs = colsum_qkv[which*192 + col];
            float v0 = r4[0]*(acc[m][n][0] - m4[0]*cs) + bv;
            float v1 = r4[1]*(acc[m][n][1] - m4[1]*cs) + bv;
            float v2 = r4[2]*(acc[m][n][2] - m4[2]*cs) + bv;
            float v3 = r4[3]*(acc[m][n][3] - m4[3]*cs) + bv;
            unsigned int p0 = cvtpk(v0,v1), p1 = cvtpk(v2,v3);
            int row = m*16 + (l>>4)*4;
            Cs[row*200 + col]     = (unsigned short)p0;
            Cs[(row+1)*200 + col] = (unsigned short)(p0>>16);
            Cs[(row+2)*200 + col] = (unsigned short)p1;
            Cs[(row+3)*200 + col] = (unsigned short)(p1>>16);
        }
    }
    __syncthreads();
    if (which < 2){
        unsigned short* dst = which==0 ? Qb : Kb;
        for (int c = tid; c < 64*24; c += 256){
            int row = c/24, cq = c-row*24;
            int4 v = *(const int4*)(Cs + row*200 + cq*8);
            *(int4*)(dst + (size_t)(t0+row)*192 + cq*8) = v;
        }
    } else {
        // transposed write: Vt[c][w*64 + j] (R9 form)
        int w = bx;
        #pragma unroll
        for (int k=0;k<6;++k){
            int c = k*32 + (tid&31); int jo = tid>>5;
            int4 ov; unsigned short* os = (unsigned short*)&ov;
            #pragma unroll
            for (int e=0;e<8;++e) os[e] = Cs[(jo*8+e)*200 + c];
            *(int4*)(Vt + (size_t)c*NW64 + w*64 + jo*8) = ov;
        }
    }
}

// ---------------- P3: per-(window,head) one-wave attention (R9) -----------
__global__ void __launch_bounds__(128) p3_attn(
    const unsigned short* Qb, const unsigned short* Kb, const unsigned short* Vt,
    const unsigned short* comb, unsigned short* attn_h)
{
    __shared__ __align__(16) char PL[2][8448];   // per-wave: P 8K | invr 256B
    int bid = blockIdx.x;
    int w = bid/3, yp = bid - w*3;
    int tid = threadIdx.x, l = tid & 63;
    int h = yp*2 + (tid>>6);
    char* P = PL[tid>>6];
    float* invr = (float*)(PL[tid>>6] + 8192);
    int q = l & 15, g = l >> 4;
    int wl = w & 63;
    int cls = (((wl>>3)==7) ? 2 : 0) + (((wl&7)==7) ? 1 : 0);

    bfx8 ak[4], bq[4];
    #pragma unroll
    for (int jt=0; jt<4; ++jt){
        int row = 16*jt + q; if (row > 48) row = 48;   // clamp: masked by comb
        size_t base = (size_t)(w*49 + row)*192 + h*32 + g*8;
        ak[jt] = *(const bfx8*)(Kb + base);
        bq[jt] = *(const bfx8*)(Qb + base);
    }
    f32x4 s[4][4];
    {
        f32x4 z = {0.f,0.f,0.f,0.f};
        #pragma unroll
        for (int it=0; it<4; ++it)
            #pragma unroll
            for (int jt=0; jt<4; ++jt)
                s[it][jt] = __builtin_amdgcn_mfma_f32_16x16x32_bf16(ak[jt], bq[it], z, 0,0,0);
    }
    const unsigned short* cb = comb + ((size_t)(cls*6 + h) << 12);
    float sum[4];
    #pragma unroll
    for (int it=0; it<4; ++it){
        #pragma unroll
        for (int jt=0; jt<4; ++jt){
            uint2 c2 = *(const uint2*)(cb + (16*it + q)*64 + 16*jt + 4*g);
            const unsigned short* cs = (const unsigned short*)&c2;
            s[it][jt][0] += u2f(cs[0]);
            s[it][jt][1] += u2f(cs[1]);
            s[it][jt][2] += u2f(cs[2]);
            s[it][jt][3] += u2f(cs[3]);
        }
        float m = s[it][0][0];
        #pragma unroll
        for (int jt=0; jt<4; ++jt)
            #pragma unroll
            for (int r=0; r<4; ++r) m = fmaxf(m, s[it][jt][r]);
        m = fmaxf(m, __shfl_xor(m, 16));
        m = fmaxf(m, __shfl_xor(m, 32));
        float su = 0.f;
        #pragma unroll
        for (int jt=0; jt<4; ++jt)
            #pragma unroll
            for (int r=0; r<4; ++r){
                float e = __expf(s[it][jt][r] - m);
                s[it][jt][r] = e;
                su += e;
            }
        su += __shfl_xor(su, 16);
        su += __shfl_xor(su, 32);
        sum[it] = su;
    }
    #pragma unroll
    for (int it=0; it<4; ++it){
        int i = 16*it + q;
        #pragma unroll
        for (int jt=0; jt<4; ++jt){
            unsigned int w0 = cvtpk(s[it][jt][0], s[it][jt][1]);
            unsigned int w1 = cvtpk(s[it][jt][2], s[it][jt][3]);
            int jb = 32*jt + 8*g;
            *(uint2*)(P + i*128 + (jb ^ ((i&7)<<4))) = make_uint2(w0, w1);
        }
    }
    if (l < 16){
        #pragma unroll
        for (int it=0; it<4; ++it) invr[16*it + l] = 1.0f / sum[it];
    }
    __syncthreads();
    f32x4 o[4][2] = {};
    #pragma unroll
    for (int kt=0; kt<2; ++kt){
        bfx8 pa[4], vb[2];
        #pragma unroll
        for (int mt=0; mt<4; ++mt){
            int r = 16*mt + q;
            pa[mt] = *(const bfx8*)(P + r*128 + ((kt*64 + g*16) ^ ((r&7)<<4)));
        }
        #pragma unroll
        for (int nt=0; nt<2; ++nt){
            int d = 16*nt + q;
            vb[nt] = *(const bfx8*)(Vt + (size_t)(h*32 + d)*NW64 + w*64 + kt*32 + g*8);
        }
        #pragma unroll
        for (int mt=0; mt<4; ++mt)
            #pragma unroll
            for (int nt=0; nt<2; ++nt)
                o[mt][nt] = __builtin_amdgcn_mfma_f32_16x16x32_bf16(pa[mt], vb[nt], o[mt][nt], 0,0,0);
    }
    #pragma unroll
    for (int mt=0; mt<4; ++mt){
        f32x4 iv = *(const f32x4*)(invr + 16*mt + 4*g);
        #pragma unroll
        for (int nt=0; nt<2; ++nt){
            int d = 16*nt + q;
            #pragma unroll
            for (int r=0; r<4; ++r){
                int i = 16*mt + 4*g + r;
                if (i < 49)
                    attn_h[((size_t)h*NTOK + (size_t)w*49 + i)*32 + d] = f2u(o[mt][nt][r] * iv[r]);
            }
        }
    }
}

// ---------------- P4: proj GEMM + residual + LN2 stats + scatter to x2 ---
__global__ void __launch_bounds__(256) p4_proj(
    const unsigned short* attn_h, const unsigned short* WprojT, const float* bproj,
    const unsigned short* X, unsigned short* x2, float* mean2, float* rstd2)
{
    __shared__ __align__(16) char L[32768];      // As 8K | Bs 24K ; bounce u16[64][200] overlaps
    __shared__ int rowg[64];
    char* As = L; char* Bs = L + 8192;
    int t0 = blockIdx.x*64;
    int tid = threadIdx.x, l = tid&63, wid = tid>>6;
    if (tid < 64){
        int t = t0 + tid; int w = t/49, n = t - w*49;
        rowg[tid] = rowmap(w, n);
    }
    __syncthreads();
    f32x4 acc[4][3] = {};
    for (int kt=0; kt<3; ++kt){
        #pragma unroll
        for (int i=0;i<2;++i){                   // A from attn_h (head-interleave)
            int c = i*256 + tid;
            int row = c>>3, kq = (c&7) ^ (row&7);
            int hh = kt*2 + (kq>>2), kin = kq&3;
            gl_lds16(attn_h + ((size_t)hh*NTOK + t0+row)*32 + kin*8,
                     As + i*4096 + wid*1024);
        }
        #pragma unroll
        for (int i=0;i<6;++i){
            int c = i*256 + tid;
            int row = c>>3, kq = (c&7) ^ (row&7);
            gl_lds16(WprojT + (size_t)row*192 + kt*64 + kq*8,
                     Bs + i*4096 + wid*1024);
        }
        __syncthreads();
        #pragma unroll
        for (int ks2=0; ks2<2; ++ks2){
            int kb = ks2*64 + ((l>>4)*16);
            bfx8 a[4], b[3];
            #pragma unroll
            for (int m=0;m<4;m++){ int r = m*16 + (l&15); a[m] = *(const bfx8*)(As + r*128 + (kb ^ ((r&7)<<4))); }
            #pragma unroll
            for (int n=0;n<3;n++){ int r = (wid*3+n)*16 + (l&15); b[n] = *(const bfx8*)(Bs + r*128 + (kb ^ ((r&7)<<4))); }
            #pragma unroll
            for (int m=0;m<4;m++)
                #pragma unroll
                for (int n=0;n<3;n++)
                    acc[m][n] = __builtin_amdgcn_mfma_f32_16x16x32_bf16(a[m], b[n], acc[m][n], 0,0,0);
        }
        __syncthreads();
    }
    unsigned short* bounce = (unsigned short*)L;  // [64][200] bf16 (x2 values)
    #pragma unroll
    for (int m=0;m<4;m++)
        #pragma unroll
        for (int n=0;n<3;n++){
            int col = (wid*3+n)*16 + (l&15);
            float bv = bproj[col];
            #pragma unroll
            for (int r=0;r<4;r++){
                int row = m*16 + (l>>4)*4 + r;
                int g = rowg[row];
                bounce[row*200 + col] = f2u(acc[m][n][r] + bv + u2f(X[(size_t)g*192 + col]));
            }
        }
    __syncthreads();
    {   // LN2 stats on the bf16 x2 row -> mean2/rstd2 (consumed by p56)
        int row = tid>>2, q = tid&3;
        float s=0.f, s2=0.f;
        #pragma unroll
        for (int i=0;i<6;i++){
            int4 v = *(const int4*)(bounce + row*200 + q*48 + i*8);
            const unsigned short* vs=(const unsigned short*)&v;
            #pragma unroll
            for(int e=0;e<8;e++){ float f=u2f(vs[e]); s+=f; s2+=f*f; }
        }
        s  += __shfl_xor(s,1);  s  += __shfl_xor(s,2);
        s2 += __shfl_xor(s2,1); s2 += __shfl_xor(s2,2);
        if (q==0){
            float m = s*(1.f/192.f);
            mean2[rowg[row]] = m;
            rstd2[rowg[row]] = rsqrtf(s2*(1.f/192.f) - m*m + EPS);
        }
    }
    for (int c = tid; c < 64*24; c += 256){
        int row = c/24, cq = c-row*24;
        int4 v = *(const int4*)(bounce + row*200 + cq*8);
        *(int4*)(x2 + (size_t)rowg[row]*192 + cq*8) = v;
    }
}

// ---------------- P56: fused MLP1+GELU+MLP2+residual (R14 + fast GELU) ----
__global__ void __launch_bounds__(256) p56_mlp(
    const unsigned short* x2, const float* mean2, const float* rstd2,
    const unsigned short* W1T, const float* b1_e, const float* colsum1,
    const unsigned short* W2T, const float* b2, float* out)
{
    __shared__ __align__(16) char L[27648 + 24576];  // region0 | Bs
    __shared__ __align__(16) float mr[64], rr[64];
    char* R0 = L;
    char* Bs = L + 27648;
    int t0 = blockIdx.x*64;
    int tid = threadIdx.x, l = tid&63, wid = tid>>6;
    if (tid < 64){ mr[tid]=mean2[t0+tid]; rr[tid]=rstd2[t0+tid]; }
    __syncthreads();
    f32x4 oacc[4][3] = {};
    for (int half=0; half<2; ++half){
        // ---- MLP1 half: hidden cols [half*192, half*192+192) ----
        f32x4 acc[4][3] = {};
        for (int kt=0; kt<3; ++kt){
            #pragma unroll
            for (int i=0;i<2;++i){               // As: x2 rows (raw, fold in epi)
                int c = i*256 + tid;
                int row = c>>3, kq = (c&7) ^ (row&7);
                gl_lds16(x2 + (size_t)(t0+row)*192 + kt*64 + kq*8,
                         R0 + i*4096 + wid*1024);
            }
            #pragma unroll
            for (int i=0;i<6;++i){               // Bs: W1T panel
                int c = i*256 + tid;
                int row = c>>3, kq = (c&7) ^ (row&7);
                gl_lds16(W1T + (size_t)(half*192+row)*192 + kt*64 + kq*8,
                         Bs + i*4096 + wid*1024);
            }
            __syncthreads();
            #pragma unroll
            for (int ks2=0; ks2<2; ++ks2){
                int kb = ks2*64 + ((l>>4)*16);
                bfx8 a[4], b[3];
                #pragma unroll
                for (int m=0;m<4;m++){ int r = m*16 + (l&15); a[m] = *(const bfx8*)(R0 + r*128 + (kb ^ ((r&7)<<4))); }
                #pragma unroll
                for (int n=0;n<3;n++){ int r = (wid*3+n)*16 + (l&15); b[n] = *(const bfx8*)(Bs + r*128 + (kb ^ ((r&7)<<4))); }
                #pragma unroll
                for (int m=0;m<4;m++)
                    #pragma unroll
                    for (int n=0;n<3;n++)
                        acc[m][n] = __builtin_amdgcn_mfma_f32_16x16x32_bf16(a[m], b[n], acc[m][n], 0,0,0);
            }
            __syncthreads();                     // all As/Bs reads done
        }
        // ---- epilogue: LN-fold + fast GELU -> H (overwrites As region) ----
        unsigned short* H = (unsigned short*)R0;  // [64][HS]
        #pragma unroll
        for (int m=0;m<4;m++){
            f32x4 m4 = *(const f32x4*)(mr + m*16 + (l>>4)*4);
            f32x4 r4 = *(const f32x4*)(rr + m*16 + (l>>4)*4);
            #pragma unroll
            for (int n=0;n<3;n++){
                int col = (wid*3+n)*16 + (l&15);
                float bv = b1_e[half*192 + col];
                float cs = colsum1[half*192 + col];
                float gv[4];
                #pragma unroll
                for (int r=0;r<4;r++){
                    float v = r4[r]*(acc[m][n][r] - m4[r]*cs) + bv;
                    gv[r] = gelu_t(v);
                }
                unsigned int p0 = cvtpk(gv[0],gv[1]), p1 = cvtpk(gv[2],gv[3]);
                int row = m*16 + (l>>4)*4;
                H[row*HS + col]     = (unsigned short)p0;
                H[(row+1)*HS + col] = (unsigned short)(p0>>16);
                H[(row+2)*HS + col] = (unsigned short)p1;
                H[(row+3)*HS + col] = (unsigned short)(p1>>16);
            }
        }
        __syncthreads();                         // H visible to all waves
        // ---- MLP2 partial: K-slice [half*192, half*192+192) ----
        for (int kt2=0; kt2<3; ++kt2){
            #pragma unroll
            for (int i=0;i<6;++i){               // Bs: W2T panel (rows = out ch)
                int c = i*256 + tid;
                int row = c>>3, kq = (c&7) ^ (row&7);
                gl_lds16(W2T + (size_t)row*384 + half*192 + kt2*64 + kq*8,
                         Bs + i*4096 + wid*1024);
            }
            __syncthreads();
            #pragma unroll
            for (int ks2=0; ks2<2; ++ks2){
                int kbB = ks2*64 + ((l>>4)*16);
                bfx8 a[4], b[3];
                #pragma unroll
                for (int m=0;m<4;m++){
                    int r = m*16 + (l&15);
                    a[m] = *(const bfx8*)(H + r*HS + kt2*64 + ks2*32 + (l>>4)*8);
                }
                #pragma unroll
                for (int n=0;n<3;n++){ int r = (wid*3+n)*16 + (l&15); b[n] = *(const bfx8*)(Bs + r*128 + (kbB ^ ((r&7)<<4))); }
                #pragma unroll
                for (int m=0;m<4;m++)
                    #pragma unroll
                    for (int n=0;n<3;n++)
                        oacc[m][n] = __builtin_amdgcn_mfma_f32_16x16x32_bf16(a[m], b[n], oacc[m][n], 0,0,0);
            }
            __syncthreads();                     // H/Bs reads done (next stage / next half)
        }
    }
    // ---- final epilogue: out = oacc + b2 + x2 residual, transposed f32 ----
    float* bounce = (float*)R0;                  // [32][197]
    int bimg = t0 / HW, hw0 = t0 - bimg*HW;
    #pragma unroll
    for (int hf=0; hf<2; ++hf){
        #pragma unroll
        for (int mm=0;mm<2;mm++){
            int m = hf*2 + mm;
            #pragma unroll
            for (int n=0;n<3;n++){
                int col = (wid*3+n)*16 + (l&15);
                float bv = b2[col];
                #pragma unroll
                for (int r=0;r<4;r++){
                    int row = m*16 + (l>>4)*4 + r;
                    bounce[(row - hf*32)*197 + col] = oacc[m][n][r] + bv + u2f(x2[(size_t)(t0+row)*192 + col]);
                }
            }
        }
        __syncthreads();
        int hw0h = hw0 + hf*32;
        for (int i = tid; i < 32*192; i += 256){
            int cc = i>>5, hwoff = i&31;
            out[(size_t)(bimg*192 + cc)*HW + hw0h + hwoff] = bounce[hwoff*197 + cc];
        }
        __syncthreads();
    }
}

extern "C" void kernel_launch(void* const* d_in, const int* in_sizes, int n_in,
                              void* d_out, int out_size, void* d_ws, size_t ws_size,
                              hipStream_t stream) {
    const float* query = (const float*)d_in[0];
    const float* gq    = (const float*)d_in[1];
    const float* nbq   = (const float*)d_in[2];
    const float* gkv   = (const float*)d_in[3];
    const float* nbkv  = (const float*)d_in[4];
    const float* Wq    = (const float*)d_in[5];
    const float* bq    = (const float*)d_in[6];
    const float* Wk    = (const float*)d_in[7];
    const float* bk    = (const float*)d_in[8];
    const float* Wv    = (const float*)d_in[9];
    const float* bv    = (const float*)d_in[10];
    const float* rpb   = (const float*)d_in[11];
    const float* Wproj = (const float*)d_in[12];
    const float* bproj = (const float*)d_in[13];
    const float* gffn  = (const float*)d_in[14];
    const float* nbffn = (const float*)d_in[15];
    const float* W1    = (const float*)d_in[16];
    const float* b1    = (const float*)d_in[17];
    const float* W2    = (const float*)d_in[18];
    const float* b2    = (const float*)d_in[19];
    const int*   rel_idx   = (const int*)d_in[20];
    const float* attn_mask = (const float*)d_in[21];
    float* out = (float*)d_out;

    char* wsb = (char*)d_ws;
    size_t off = 0;
    auto alloc = [&](size_t bytes)->void*{
        void* p = wsb + off; off += (bytes + 255) & ~(size_t)255; return p;
    };
    unsigned short* X      = (unsigned short*)alloc((size_t)NTOK*192*2);
    unsigned short* Qb     = (unsigned short*)alloc((size_t)NTOK*192*2);
    unsigned short* Kb     = (unsigned short*)alloc((size_t)NTOK*192*2);
    unsigned short* Vt     = (unsigned short*)alloc((size_t)192*NW64*2);
    unsigned short* attn_h = (unsigned short*)alloc((size_t)NH*NTOK*32*2);
    float* mean  = (float*)alloc((size_t)NTOK*4);
    float* rstd  = (float*)alloc((size_t)NTOK*4);
    unsigned short* WqkvT = (unsigned short*)alloc(110592*2);
    unsigned short* WprojT= (unsigned short*)alloc(36864*2);
    unsigned short* W1T   = (unsigned short*)alloc(73728*2);
    unsigned short* W2T   = (unsigned short*)alloc(73728*2);
    float* bias_qkv = (float*)alloc(576*4);
    float* b1_e     = (float*)alloc(384*4);
    unsigned short* comb = (unsigned short*)alloc((size_t)4*6*64*64*2);
    float* colsum_qkv = (float*)alloc(576*4);
    float* colsum1    = (float*)alloc(384*4);
    unsigned short* x2     = Vt;     // alias: Vt dead after p3 (100MB >= 77MB)
    float* mean2 = mean;             // alias: LN1 stats dead after p2
    float* rstd2 = rstd;

    hipLaunchKernelGGL(p0_prep, dim3(1544), dim3(256), 0, stream,
        Wq, bq, Wk, bk, Wv, bv, Wproj, W1, b1, W2,
        gq, nbq, gkv, nbkv, gffn, nbffn, rpb, rel_idx, attn_mask,
        WqkvT, WprojT, W1T, W2T, bias_qkv, b1_e, comb, colsum_qkv, colsum1);
    hipLaunchKernelGGL(p1_transpose_stats, dim3(64*98), dim3(256), 0, stream,
        query, X, mean, rstd);
    hipLaunchKernelGGL(p2_qkv, dim3(NWIN, 3), dim3(256), 0, stream,
        X, mean, rstd, WqkvT, bias_qkv, colsum_qkv, Qb, Kb, Vt);
    hipLaunchKernelGGL(p3_attn, dim3(NWIN*3), dim3(128), 0, stream,
        Qb, Kb, Vt, comb, attn_h);
    hipLaunchKernelGGL(p4_proj, dim3(NTOK/64), dim3(256), 0, stream,
        attn_h, WprojT, bproj, X, x2, mean2, rstd2);
    hipLaunchKernelGGL(p56_mlp, dim3(NTOK/64), dim3(256), 0, stream,
        x2, mean2, rstd2, W1T, b1_e, colsum1, W2T, b2, out);
}

// Round 18
// 461.114 us; speedup vs baseline: 1.0252x; 1.0252x over previous
//
#include <hip/hip_runtime.h>
#include <hip/hip_bf16.h>
#include <math.h>

#define B_IMG 64
#define C_DIM 192
#define HW 3136
#define NTOK (B_IMG*HW)      // 200704
#define NH 6
#define HD 32
#define WSZ 7
#define NTW 49
#define SS 3
#define NWIN 4096
#define NW64 262144          // NWIN*64, padded window-aligned token stride
#define MLPH 384
#define EPS 1e-5f
#define HS 216               // H tile stride (u16): rows 16B-aligned

typedef __attribute__((ext_vector_type(8))) short bfx8;
typedef __attribute__((ext_vector_type(4))) float f32x4;

__device__ __forceinline__ float u2f(unsigned short u){
    union { float f; unsigned int i; } v; v.i = ((unsigned int)u) << 16; return v.f;
}
__device__ __forceinline__ unsigned short f2u(float f){
    union { float f; unsigned int i; } v; v.f = f;
    unsigned int r = v.i + 0x7FFF + ((v.i >> 16) & 1);
    return (unsigned short)(r >> 16);
}
// packed f32x2 -> bf16x2 (RNE), 1 instruction
__device__ __forceinline__ unsigned int cvtpk(float lo, float hi){
    unsigned int r;
    asm("v_cvt_pk_bf16_f32 %0, %1, %2" : "=v"(r) : "v"(lo), "v"(hi));
    return r;
}
// async 16B global->LDS DMA (no VGPR round-trip). LDS dest = wave-uniform
// base + lane*16; global src is per-lane (XOR-permuted to realize swizzle).
__device__ __forceinline__ void gl_lds16(const void* g, void* l){
    __builtin_amdgcn_global_load_lds(
        (const __attribute__((address_space(1))) unsigned int*)g,
        (__attribute__((address_space(3))) unsigned int*)l, 16, 0, 0);
}
// tanh-form GELU, sigmoid via RAW v_rcp_f32 (1 inst, ~1ulp << bf16 quant):
// gelu(v) = v * rcp(1 + exp(-1.59576912(v + 0.044715 v^3)))
__device__ __forceinline__ float gelu_t(float v){
    float u = -1.5957691216057308f * v * (1.0f + 0.044715f*v*v);
    return v * __builtin_amdgcn_rcpf(1.0f + __expf(u));
}

__device__ __forceinline__ int rowmap(int w_, int n){
    int b  = w_ >> 6, wl = w_ & 63;
    int wy = wl >> 3, wx = wl & 7;
    int ty = n / 7,  tx = n % 7;
    int h = wy*7 + ty + SS; if (h >= 56) h -= 56;
    int w = wx*7 + tx + SS; if (w >= 56) w -= 56;
    return b*HW + h*56 + w;
}

// ---------------- P0: weight prep (fold LN affine + scale, bf16 transpose) ----
__global__ void __launch_bounds__(256) p0_prep(
    const float* Wq, const float* bq, const float* Wk, const float* bk,
    const float* Wv, const float* bv, const float* Wproj,
    const float* W1, const float* b1, const float* W2,
    const float* gq, const float* nbq, const float* gkv, const float* nbkv,
    const float* gffn, const float* nbffn,
    const float* rpb, const int* rel_idx, const float* attn_mask,
    unsigned short* WqkvT, unsigned short* WprojT, unsigned short* W1T, unsigned short* W2T,
    float* bias_qkv, float* b1_e, unsigned short* comb,
    float* colsum_qkv, float* colsum1)
{
    const float scale = 0.17677669529663687f;   // 1/sqrt(32)
    int id = blockIdx.x*256 + threadIdx.x;
    if (id < 110592){                       // WqkvT [576][192]
        int j = id/192, c = id - j*192;
        int which = j/192, col = j - which*192;
        float v;
        if (which==0)      v = scale*gq[c]*Wq[c*192+col];
        else if (which==1) v = gkv[c]*Wk[c*192+col];
        else               v = gkv[c]*Wv[c*192+col];
        WqkvT[id] = f2u(v);
    } else if (id < 147456){                // WprojT [192][192]
        int t = id-110592; int co = t/192, k = t-co*192;
        WprojT[t] = f2u(Wproj[k*192+co]);
    } else if (id < 221184){                // W1T [384][192]
        int t = id-147456; int j = t/192, c = t-j*192;
        W1T[t] = f2u(gffn[c]*W1[c*384+j]);
    } else if (id < 294912){                // W2T [192][384]
        int t = id-221184; int co = t/384, k = t-co*384;
        W2T[t] = f2u(W2[k*192+co]);
    } else if (id < 295488){                // bias_qkv [576]
        int j = id-294912; int which=j/192, col=j-which*192;
        float s;
        if (which==0){ s = bq[col]; for(int c=0;c<192;c++) s += nbq[c]*Wq[c*192+col]; s*=scale; }
        else if (which==1){ s = bk[col]; for(int c=0;c<192;c++) s += nbkv[c]*Wk[c*192+col]; }
        else { s = bv[col]; for(int c=0;c<192;c++) s += nbkv[c]*Wv[c*192+col]; }
        bias_qkv[j] = s;
    } else if (id < 295872){                // b1_e [384]
        int j = id-295488; float s = b1[j];
        for(int c=0;c<192;c++) s += nbffn[c]*W1[c*384+j];
        b1_e[j] = s;
    } else if (id < 394176){                // comb [4][6][64][64] bf16
        int t = id-295872;
        int j = t & 63, i = (t>>6) & 63;
        int rest = t >> 12;                 // 0..23
        int h = rest % 6, cls = rest / 6;
        float v = -1e30f;
        if (i < 49 && j < 49){
            int wlrep = (cls>>1)*56 + (cls&1)*7;
            v = rpb[rel_idx[i*49+j]*6 + h] + attn_mask[wlrep*2401 + i*49 + j];
        }
        comb[t] = f2u(v);
    } else if (id < 394752){                // colsum_qkv [576]
        int j = id-394176; int which=j/192, col=j-which*192;
        float s = 0.f;
        if (which==0){ for(int c=0;c<192;c++) s += gq[c]*Wq[c*192+col]; s*=scale; }
        else if (which==1){ for(int c=0;c<192;c++) s += gkv[c]*Wk[c*192+col]; }
        else { for(int c=0;c<192;c++) s += gkv[c]*Wv[c*192+col]; }
        colsum_qkv[j] = s;
    } else if (id < 395136){                // colsum1 [384]
        int j = id-394752; float s = 0.f;
        for(int c=0;c<192;c++) s += gffn[c]*W1[c*384+j];
        colsum1[j] = s;
    }
}

// ---------------- P1: (B,C,HW) -> token-major bf16 X + LN stats ----------
__global__ void __launch_bounds__(256) p1_transpose_stats(
    const float* q, unsigned short* X, float* mean, float* rstd)
{
    __shared__ float t[32*193];
    __shared__ float ms[32], rs[32];
    int blk = blockIdx.x;
    int b = blk / 98, tile = blk - b*98;
    int hw0 = tile*32;
    const float* qb = q + (size_t)b*C_DIM*HW;
    int hw_off = threadIdx.x & 31, csub = threadIdx.x >> 5;
    for (int cb = 0; cb < 192; cb += 8){
        int c = cb + csub;
        t[hw_off*193 + c] = qb[(size_t)c*HW + hw0 + hw_off];
    }
    __syncthreads();
    {   // stats: 8 lanes per token
        int tt = threadIdx.x >> 3, qq = threadIdx.x & 7;
        float s=0.f, s2=0.f;
        #pragma unroll
        for (int i=0;i<24;i++){ float v = t[tt*193 + qq*24 + i]; s+=v; s2+=v*v; }
        s  += __shfl_xor(s,1);  s  += __shfl_xor(s,2);  s  += __shfl_xor(s,4);
        s2 += __shfl_xor(s2,1); s2 += __shfl_xor(s2,2); s2 += __shfl_xor(s2,4);
        if (qq==0){
            float m = s*(1.f/192.f);
            ms[tt] = m; rs[tt] = rsqrtf(s2*(1.f/192.f) - m*m + EPS);
        }
    }
    __syncthreads();
    int g0 = b*HW + hw0;
    if (threadIdx.x < 32){
        mean[g0+threadIdx.x] = ms[threadIdx.x];
        rstd[g0+threadIdx.x] = rs[threadIdx.x];
    }
    for (int i = threadIdx.x; i < 32*24; i += 256){
        int tt = i/24, cq = i - tt*24;
        int base = tt*193 + cq*8;
        int4 vr; unsigned int* pu = (unsigned int*)&vr;
        pu[0] = cvtpk(t[base+0], t[base+1]);
        pu[1] = cvtpk(t[base+2], t[base+3]);
        pu[2] = cvtpk(t[base+4], t[base+5]);
        pu[3] = cvtpk(t[base+6], t[base+7]);
        *(int4*)(X + (size_t)(g0+tt)*192 + cq*8) = vr;
    }
}

// ---------------- P2: QKV GEMM, async staging + rank-1 LN fold (R9) ------
__global__ void __launch_bounds__(256) p2_qkv(
    const unsigned short* X, const float* mean, const float* rstd,
    const unsigned short* WqkvT, const float* bias_qkv, const float* colsum_qkv,
    unsigned short* Qb, unsigned short* Kb, unsigned short* Vt)
{
    __shared__ __align__(16) char L[32768];      // As 8K | Bs 24K ; Cs 25.6K overlaps
    __shared__ int rowg[64];
    __shared__ __align__(16) float mr[64], rr[64];
    char* As = L; char* Bs = L + 8192;
    int which = blockIdx.y, bx = blockIdx.x;
    if (which < 2 && bx >= 3136) return;
    int t0 = bx*64;
    int tid = threadIdx.x, l = tid&63, wid = tid>>6;
    if (tid < 64){
        int w, n;
        if (which == 2){ w = bx; n = tid > 48 ? 48 : tid; }
        else { int t = t0 + tid; w = t/49; n = t - w*49; }
        int g = rowmap(w, n); rowg[tid]=g; mr[tid]=mean[g]; rr[tid]=rstd[g];
    }
    __syncthreads();
    f32x4 acc[4][3] = {};
    for (int kt=0; kt<3; ++kt){
        #pragma unroll
        for (int i=0;i<2;++i){                   // A: 512 slots
            int c = i*256 + tid;
            int row = c>>3, kq = (c&7) ^ (row&7);
            gl_lds16(X + (size_t)rowg[row]*192 + kt*64 + kq*8,
                     As + i*4096 + wid*1024);
        }
        #pragma unroll
        for (int i=0;i<6;++i){                   // B: 1536 slots
            int c = i*256 + tid;
            int row = c>>3, kq = (c&7) ^ (row&7);
            gl_lds16(WqkvT + (size_t)(which*192+row)*192 + kt*64 + kq*8,
                     Bs + i*4096 + wid*1024);
        }
        __syncthreads();
        #pragma unroll
        for (int ks2=0; ks2<2; ++ks2){
            int kb = ks2*64 + ((l>>4)*16);
            bfx8 a[4], b[3];
            #pragma unroll
            for (int m=0;m<4;m++){ int r = m*16 + (l&15); a[m] = *(const bfx8*)(As + r*128 + (kb ^ ((r&7)<<4))); }
            #pragma unroll
            for (int n=0;n<3;n++){ int r = (wid*3+n)*16 + (l&15); b[n] = *(const bfx8*)(Bs + r*128 + (kb ^ ((r&7)<<4))); }
            #pragma unroll
            for (int m=0;m<4;m++)
                #pragma unroll
                for (int n=0;n<3;n++)
                    acc[m][n] = __builtin_amdgcn_mfma_f32_16x16x32_bf16(a[m], b[n], acc[m][n], 0,0,0);
        }
        __syncthreads();
    }
    unsigned short* Cs = (unsigned short*)L;     // [64][200]
    #pragma unroll
    for (int m=0;m<4;m++){
        f32x4 m4 = *(const f32x4*)(mr + m*16 + (l>>4)*4);
        f32x4 r4 = *(const f32x4*)(rr + m*16 + (l>>4)*4);
        #pragma unroll
        for (int n=0;n<3;n++){
            int col = (wid*3+n)*16 + (l&15);
            float bv = bias_qkv[which*192 + col];
            float cs = colsum_qkv[which*192 + col];
            float v0 = r4[0]*(acc[m][n][0] - m4[0]*cs) + bv;
            float v1 = r4[1]*(acc[m][n][1] - m4[1]*cs) + bv;
            float v2 = r4[2]*(acc[m][n][2] - m4[2]*cs) + bv;
            float v3 = r4[3]*(acc[m][n][3] - m4[3]*cs) + bv;
            unsigned int p0 = cvtpk(v0,v1), p1 = cvtpk(v2,v3);
            int row = m*16 + (l>>4)*4;
            Cs[row*200 + col]     = (unsigned short)p0;
            Cs[(row+1)*200 + col] = (unsigned short)(p0>>16);
            Cs[(row+2)*200 + col] = (unsigned short)p1;
            Cs[(row+3)*200 + col] = (unsigned short)(p1>>16);
        }
    }
    __syncthreads();
    if (which < 2){
        unsigned short* dst = which==0 ? Qb : Kb;
        for (int c = tid; c < 64*24; c += 256){
            int row = c/24, cq = c-row*24;
            int4 v = *(const int4*)(Cs + row*200 + cq*8);
            *(int4*)(dst + (size_t)(t0+row)*192 + cq*8) = v;
        }
    } else {
        // transposed write: Vt[c][w*64 + j] (R9 form)
        int w = bx;
        #pragma unroll
        for (int k=0;k<6;++k){
            int c = k*32 + (tid&31); int jo = tid>>5;
            int4 ov; unsigned short* os = (unsigned short*)&ov;
            #pragma unroll
            for (int e=0;e<8;++e) os[e] = Cs[(jo*8+e)*200 + c];
            *(int4*)(Vt + (size_t)c*NW64 + w*64 + jo*8) = ov;
        }
    }
}

// ---------------- P3: per-(window,head) one-wave attention (R9) -----------
__global__ void __launch_bounds__(128) p3_attn(
    const unsigned short* Qb, const unsigned short* Kb, const unsigned short* Vt,
    const unsigned short* comb, unsigned short* attn_h)
{
    __shared__ __align__(16) char PL[2][8448];   // per-wave: P 8K | invr 256B
    int bid = blockIdx.x;
    int w = bid/3, yp = bid - w*3;
    int tid = threadIdx.x, l = tid & 63;
    int h = yp*2 + (tid>>6);
    char* P = PL[tid>>6];
    float* invr = (float*)(PL[tid>>6] + 8192);
    int q = l & 15, g = l >> 4;
    int wl = w & 63;
    int cls = (((wl>>3)==7) ? 2 : 0) + (((wl&7)==7) ? 1 : 0);

    bfx8 ak[4], bq[4];
    #pragma unroll
    for (int jt=0; jt<4; ++jt){
        int row = 16*jt + q; if (row > 48) row = 48;   // clamp: masked by comb
        size_t base = (size_t)(w*49 + row)*192 + h*32 + g*8;
        ak[jt] = *(const bfx8*)(Kb + base);
        bq[jt] = *(const bfx8*)(Qb + base);
    }
    f32x4 s[4][4];
    {
        f32x4 z = {0.f,0.f,0.f,0.f};
        #pragma unroll
        for (int it=0; it<4; ++it)
            #pragma unroll
            for (int jt=0; jt<4; ++jt)
                s[it][jt] = __builtin_amdgcn_mfma_f32_16x16x32_bf16(ak[jt], bq[it], z, 0,0,0);
    }
    const unsigned short* cb = comb + ((size_t)(cls*6 + h) << 12);
    float sum[4];
    #pragma unroll
    for (int it=0; it<4; ++it){
        #pragma unroll
        for (int jt=0; jt<4; ++jt){
            uint2 c2 = *(const uint2*)(cb + (16*it + q)*64 + 16*jt + 4*g);
            const unsigned short* cs = (const unsigned short*)&c2;
            s[it][jt][0] += u2f(cs[0]);
            s[it][jt][1] += u2f(cs[1]);
            s[it][jt][2] += u2f(cs[2]);
            s[it][jt][3] += u2f(cs[3]);
        }
        float m = s[it][0][0];
        #pragma unroll
        for (int jt=0; jt<4; ++jt)
            #pragma unroll
            for (int r=0; r<4; ++r) m = fmaxf(m, s[it][jt][r]);
        m = fmaxf(m, __shfl_xor(m, 16));
        m = fmaxf(m, __shfl_xor(m, 32));
        float su = 0.f;
        #pragma unroll
        for (int jt=0; jt<4; ++jt)
            #pragma unroll
            for (int r=0; r<4; ++r){
                float e = __expf(s[it][jt][r] - m);
                s[it][jt][r] = e;
                su += e;
            }
        su += __shfl_xor(su, 16);
        su += __shfl_xor(su, 32);
        sum[it] = su;
    }
    #pragma unroll
    for (int it=0; it<4; ++it){
        int i = 16*it + q;
        #pragma unroll
        for (int jt=0; jt<4; ++jt){
            unsigned int w0 = cvtpk(s[it][jt][0], s[it][jt][1]);
            unsigned int w1 = cvtpk(s[it][jt][2], s[it][jt][3]);
            int jb = 32*jt + 8*g;
            *(uint2*)(P + i*128 + (jb ^ ((i&7)<<4))) = make_uint2(w0, w1);
        }
    }
    if (l < 16){
        #pragma unroll
        for (int it=0; it<4; ++it) invr[16*it + l] = 1.0f / sum[it];
    }
    __syncthreads();
    f32x4 o[4][2] = {};
    #pragma unroll
    for (int kt=0; kt<2; ++kt){
        bfx8 pa[4], vb[2];
        #pragma unroll
        for (int mt=0; mt<4; ++mt){
            int r = 16*mt + q;
            pa[mt] = *(const bfx8*)(P + r*128 + ((kt*64 + g*16) ^ ((r&7)<<4)));
        }
        #pragma unroll
        for (int nt=0; nt<2; ++nt){
            int d = 16*nt + q;
            vb[nt] = *(const bfx8*)(Vt + (size_t)(h*32 + d)*NW64 + w*64 + kt*32 + g*8);
        }
        #pragma unroll
        for (int mt=0; mt<4; ++mt)
            #pragma unroll
            for (int nt=0; nt<2; ++nt)
                o[mt][nt] = __builtin_amdgcn_mfma_f32_16x16x32_bf16(pa[mt], vb[nt], o[mt][nt], 0,0,0);
    }
    #pragma unroll
    for (int mt=0; mt<4; ++mt){
        f32x4 iv = *(const f32x4*)(invr + 16*mt + 4*g);
        #pragma unroll
        for (int nt=0; nt<2; ++nt){
            int d = 16*nt + q;
            #pragma unroll
            for (int r=0; r<4; ++r){
                int i = 16*mt + 4*g + r;
                if (i < 49)
                    attn_h[((size_t)h*NTOK + (size_t)w*49 + i)*32 + d] = f2u(o[mt][nt][r] * iv[r]);
            }
        }
    }
}

// ---------------- P4: proj GEMM + residual + LN2 stats + scatter to x2 ---
__global__ void __launch_bounds__(256) p4_proj(
    const unsigned short* attn_h, const unsigned short* WprojT, const float* bproj,
    const unsigned short* X, unsigned short* x2, float* mean2, float* rstd2)
{
    __shared__ __align__(16) char L[32768];      // As 8K | Bs 24K ; bounce u16[64][200] overlaps
    __shared__ int rowg[64];
    char* As = L; char* Bs = L + 8192;
    int t0 = blockIdx.x*64;
    int tid = threadIdx.x, l = tid&63, wid = tid>>6;
    if (tid < 64){
        int t = t0 + tid; int w = t/49, n = t - w*49;
        rowg[tid] = rowmap(w, n);
    }
    __syncthreads();
    f32x4 acc[4][3] = {};
    for (int kt=0; kt<3; ++kt){
        #pragma unroll
        for (int i=0;i<2;++i){                   // A from attn_h (head-interleave)
            int c = i*256 + tid;
            int row = c>>3, kq = (c&7) ^ (row&7);
            int hh = kt*2 + (kq>>2), kin = kq&3;
            gl_lds16(attn_h + ((size_t)hh*NTOK + t0+row)*32 + kin*8,
                     As + i*4096 + wid*1024);
        }
        #pragma unroll
        for (int i=0;i<6;++i){
            int c = i*256 + tid;
            int row = c>>3, kq = (c&7) ^ (row&7);
            gl_lds16(WprojT + (size_t)row*192 + kt*64 + kq*8,
                     Bs + i*4096 + wid*1024);
        }
        __syncthreads();
        #pragma unroll
        for (int ks2=0; ks2<2; ++ks2){
            int kb = ks2*64 + ((l>>4)*16);
            bfx8 a[4], b[3];
            #pragma unroll
            for (int m=0;m<4;m++){ int r = m*16 + (l&15); a[m] = *(const bfx8*)(As + r*128 + (kb ^ ((r&7)<<4))); }
            #pragma unroll
            for (int n=0;n<3;n++){ int r = (wid*3+n)*16 + (l&15); b[n] = *(const bfx8*)(Bs + r*128 + (kb ^ ((r&7)<<4))); }
            #pragma unroll
            for (int m=0;m<4;m++)
                #pragma unroll
                for (int n=0;n<3;n++)
                    acc[m][n] = __builtin_amdgcn_mfma_f32_16x16x32_bf16(a[m], b[n], acc[m][n], 0,0,0);
        }
        __syncthreads();
    }
    unsigned short* bounce = (unsigned short*)L;  // [64][200] bf16 (x2 values)
    #pragma unroll
    for (int m=0;m<4;m++)
        #pragma unroll
        for (int n=0;n<3;n++){
            int col = (wid*3+n)*16 + (l&15);
            float bv = bproj[col];
            #pragma unroll
            for (int r=0;r<4;r++){
                int row = m*16 + (l>>4)*4 + r;
                int g = rowg[row];
                bounce[row*200 + col] = f2u(acc[m][n][r] + bv + u2f(X[(size_t)g*192 + col]));
            }
        }
    __syncthreads();
    {   // LN2 stats on the bf16 x2 row -> mean2/rstd2 (consumed by p56)
        int row = tid>>2, q = tid&3;
        float s=0.f, s2=0.f;
        #pragma unroll
        for (int i=0;i<6;i++){
            int4 v = *(const int4*)(bounce + row*200 + q*48 + i*8);
            const unsigned short* vs=(const unsigned short*)&v;
            #pragma unroll
            for(int e=0;e<8;e++){ float f=u2f(vs[e]); s+=f; s2+=f*f; }
        }
        s  += __shfl_xor(s,1);  s  += __shfl_xor(s,2);
        s2 += __shfl_xor(s2,1); s2 += __shfl_xor(s2,2);
        if (q==0){
            float m = s*(1.f/192.f);
            mean2[rowg[row]] = m;
            rstd2[rowg[row]] = rsqrtf(s2*(1.f/192.f) - m*m + EPS);
        }
    }
    for (int c = tid; c < 64*24; c += 256){
        int row = c/24, cq = c-row*24;
        int4 v = *(const int4*)(bounce + row*200 + cq*8);
        *(int4*)(x2 + (size_t)rowg[row]*192 + cq*8) = v;
    }
}

// ---------------- P56: fused MLP1+GELU+MLP2+residual (R16 + rcp GELU) -----
__global__ void __launch_bounds__(256) p56_mlp(
    const unsigned short* x2, const float* mean2, const float* rstd2,
    const unsigned short* W1T, const float* b1_e, const float* colsum1,
    const unsigned short* W2T, const float* b2, float* out)
{
    __shared__ __align__(16) char L[27648 + 24576];  // region0 | Bs
    __shared__ __align__(16) float mr[64], rr[64];
    char* R0 = L;
    char* Bs = L + 27648;
    int t0 = blockIdx.x*64;
    int tid = threadIdx.x, l = tid&63, wid = tid>>6;
    if (tid < 64){ mr[tid]=mean2[t0+tid]; rr[tid]=rstd2[t0+tid]; }
    __syncthreads();
    f32x4 oacc[4][3] = {};
    for (int half=0; half<2; ++half){
        // ---- MLP1 half: hidden cols [half*192, half*192+192) ----
        f32x4 acc[4][3] = {};
        for (int kt=0; kt<3; ++kt){
            #pragma unroll
            for (int i=0;i<2;++i){               // As: x2 rows (raw, fold in epi)
                int c = i*256 + tid;
                int row = c>>3, kq = (c&7) ^ (row&7);
                gl_lds16(x2 + (size_t)(t0+row)*192 + kt*64 + kq*8,
                         R0 + i*4096 + wid*1024);
            }
            #pragma unroll
            for (int i=0;i<6;++i){               // Bs: W1T panel
                int c = i*256 + tid;
                int row = c>>3, kq = (c&7) ^ (row&7);
                gl_lds16(W1T + (size_t)(half*192+row)*192 + kt*64 + kq*8,
                         Bs + i*4096 + wid*1024);
            }
            __syncthreads();
            #pragma unroll
            for (int ks2=0; ks2<2; ++ks2){
                int kb = ks2*64 + ((l>>4)*16);
                bfx8 a[4], b[3];
                #pragma unroll
                for (int m=0;m<4;m++){ int r = m*16 + (l&15); a[m] = *(const bfx8*)(R0 + r*128 + (kb ^ ((r&7)<<4))); }
                #pragma unroll
                for (int n=0;n<3;n++){ int r = (wid*3+n)*16 + (l&15); b[n] = *(const bfx8*)(Bs + r*128 + (kb ^ ((r&7)<<4))); }
                #pragma unroll
                for (int m=0;m<4;m++)
                    #pragma unroll
                    for (int n=0;n<3;n++)
                        acc[m][n] = __builtin_amdgcn_mfma_f32_16x16x32_bf16(a[m], b[n], acc[m][n], 0,0,0);
            }
            __syncthreads();                     // all As/Bs reads done
        }
        // ---- epilogue: LN-fold + rcp GELU -> H (overwrites As region) ----
        unsigned short* H = (unsigned short*)R0;  // [64][HS]
        #pragma unroll
        for (int m=0;m<4;m++){
            f32x4 m4 = *(const f32x4*)(mr + m*16 + (l>>4)*4);
            f32x4 r4 = *(const f32x4*)(rr + m*16 + (l>>4)*4);
            #pragma unroll
            for (int n=0;n<3;n++){
                int col = (wid*3+n)*16 + (l&15);
                float bv = b1_e[half*192 + col];
                float cs = colsum1[half*192 + col];
                float gv[4];
                #pragma unroll
                for (int r=0;r<4;r++){
                    float v = r4[r]*(acc[m][n][r] - m4[r]*cs) + bv;
                    gv[r] = gelu_t(v);
                }
                unsigned int p0 = cvtpk(gv[0],gv[1]), p1 = cvtpk(gv[2],gv[3]);
                int row = m*16 + (l>>4)*4;
                H[row*HS + col]     = (unsigned short)p0;
                H[(row+1)*HS + col] = (unsigned short)(p0>>16);
                H[(row+2)*HS + col] = (unsigned short)p1;
                H[(row+3)*HS + col] = (unsigned short)(p1>>16);
            }
        }
        __syncthreads();                         // H visible to all waves
        // ---- MLP2 partial: K-slice [half*192, half*192+192) ----
        for (int kt2=0; kt2<3; ++kt2){
            #pragma unroll
            for (int i=0;i<6;++i){               // Bs: W2T panel (rows = out ch)
                int c = i*256 + tid;
                int row = c>>3, kq = (c&7) ^ (row&7);
                gl_lds16(W2T + (size_t)row*384 + half*192 + kt2*64 + kq*8,
                         Bs + i*4096 + wid*1024);
            }
            __syncthreads();
            #pragma unroll
            for (int ks2=0; ks2<2; ++ks2){
                int kbB = ks2*64 + ((l>>4)*16);
                bfx8 a[4], b[3];
                #pragma unroll
                for (int m=0;m<4;m++){
                    int r = m*16 + (l&15);
                    a[m] = *(const bfx8*)(H + r*HS + kt2*64 + ks2*32 + (l>>4)*8);
                }
                #pragma unroll
                for (int n=0;n<3;n++){ int r = (wid*3+n)*16 + (l&15); b[n] = *(const bfx8*)(Bs + r*128 + (kbB ^ ((r&7)<<4))); }
                #pragma unroll
                for (int m=0;m<4;m++)
                    #pragma unroll
                    for (int n=0;n<3;n++)
                        oacc[m][n] = __builtin_amdgcn_mfma_f32_16x16x32_bf16(a[m], b[n], oacc[m][n], 0,0,0);
            }
            __syncthreads();                     // H/Bs reads done (next stage / next half)
        }
    }
    // ---- final epilogue: out = oacc + b2 + x2 residual, transposed f32 ----
    float* bounce = (float*)R0;                  // [32][197]
    int bimg = t0 / HW, hw0 = t0 - bimg*HW;
    #pragma unroll
    for (int hf=0; hf<2; ++hf){
        #pragma unroll
        for (int mm=0;mm<2;mm++){
            int m = hf*2 + mm;
            #pragma unroll
            for (int n=0;n<3;n++){
                int col = (wid*3+n)*16 + (l&15);
                float bv = b2[col];
                #pragma unroll
                for (int r=0;r<4;r++){
                    int row = m*16 + (l>>4)*4 + r;
                    bounce[(row - hf*32)*197 + col] = oacc[m][n][r] + bv + u2f(x2[(size_t)(t0+row)*192 + col]);
                }
            }
        }
        __syncthreads();
        int hw0h = hw0 + hf*32;
        for (int i = tid; i < 32*192; i += 256){
            int cc = i>>5, hwoff = i&31;
            out[(size_t)(bimg*192 + cc)*HW + hw0h + hwoff] = bounce[hwoff*197 + cc];
        }
        __syncthreads();
    }
}

extern "C" void kernel_launch(void* const* d_in, const int* in_sizes, int n_in,
                              void* d_out, int out_size, void* d_ws, size_t ws_size,
                              hipStream_t stream) {
    const float* query = (const float*)d_in[0];
    const float* gq    = (const float*)d_in[1];
    const float* nbq   = (const float*)d_in[2];
    const float* gkv   = (const float*)d_in[3];
    const float* nbkv  = (const float*)d_in[4];
    const float* Wq    = (const float*)d_in[5];
    const float* bq    = (const float*)d_in[6];
    const float* Wk    = (const float*)d_in[7];
    const float* bk    = (const float*)d_in[8];
    const float* Wv    = (const float*)d_in[9];
    const float* bv    = (const float*)d_in[10];
    const float* rpb   = (const float*)d_in[11];
    const float* Wproj = (const float*)d_in[12];
    const float* bproj = (const float*)d_in[13];
    const float* gffn  = (const float*)d_in[14];
    const float* nbffn = (const float*)d_in[15];
    const float* W1    = (const float*)d_in[16];
    const float* b1    = (const float*)d_in[17];
    const float* W2    = (const float*)d_in[18];
    const float* b2    = (const float*)d_in[19];
    const int*   rel_idx   = (const int*)d_in[20];
    const float* attn_mask = (const float*)d_in[21];
    float* out = (float*)d_out;

    char* wsb = (char*)d_ws;
    size_t off = 0;
    auto alloc = [&](size_t bytes)->void*{
        void* p = wsb + off; off += (bytes + 255) & ~(size_t)255; return p;
    };
    unsigned short* X      = (unsigned short*)alloc((size_t)NTOK*192*2);
    unsigned short* Qb     = (unsigned short*)alloc((size_t)NTOK*192*2);
    unsigned short* Kb     = (unsigned short*)alloc((size_t)NTOK*192*2);
    unsigned short* Vt     = (unsigned short*)alloc((size_t)192*NW64*2);
    unsigned short* attn_h = (unsigned short*)alloc((size_t)NH*NTOK*32*2);
    float* mean  = (float*)alloc((size_t)NTOK*4);
    float* rstd  = (float*)alloc((size_t)NTOK*4);
    unsigned short* WqkvT = (unsigned short*)alloc(110592*2);
    unsigned short* WprojT= (unsigned short*)alloc(36864*2);
    unsigned short* W1T   = (unsigned short*)alloc(73728*2);
    unsigned short* W2T   = (unsigned short*)alloc(73728*2);
    float* bias_qkv = (float*)alloc(576*4);
    float* b1_e     = (float*)alloc(384*4);
    unsigned short* comb = (unsigned short*)alloc((size_t)4*6*64*64*2);
    float* colsum_qkv = (float*)alloc(576*4);
    float* colsum1    = (float*)alloc(384*4);
    unsigned short* x2     = Vt;     // alias: Vt dead after p3 (100MB >= 77MB)
    float* mean2 = mean;             // alias: LN1 stats dead after p2
    float* rstd2 = rstd;

    hipLaunchKernelGGL(p0_prep, dim3(1544), dim3(256), 0, stream,
        Wq, bq, Wk, bk, Wv, bv, Wproj, W1, b1, W2,
        gq, nbq, gkv, nbkv, gffn, nbffn, rpb, rel_idx, attn_mask,
        WqkvT, WprojT, W1T, W2T, bias_qkv, b1_e, comb, colsum_qkv, colsum1);
    hipLaunchKernelGGL(p1_transpose_stats, dim3(64*98), dim3(256), 0, stream,
        query, X, mean, rstd);
    hipLaunchKernelGGL(p2_qkv, dim3(NWIN, 3), dim3(256), 0, stream,
        X, mean, rstd, WqkvT, bias_qkv, colsum_qkv, Qb, Kb, Vt);
    hipLaunchKernelGGL(p3_attn, dim3(NWIN*3), dim3(128), 0, stream,
        Qb, Kb, Vt, comb, attn_h);
    hipLaunchKernelGGL(p4_proj, dim3(NTOK/64), dim3(256), 0, stream,
        attn_h, WprojT, bproj, X, x2, mean2, rstd2);
    hipLaunchKernelGGL(p56_mlp, dim3(NTOK/64), dim3(256), 0, stream,
        x2, mean2, rstd2, W1T, b1_e, colsum1, W2T, b2, out);
}